// Round 2
// baseline (392.499 us; speedup 1.0000x reference)
//
#include <hip/hip_runtime.h>
#include <math.h>

#define O_  32
#define I_  32
#define K_  13
#define N_  4096
#define IK  (I_ * K_)     // 416
#define OIK (O_ * IK)     // 13312
#define NB  4             // n's per block

typedef float f32x4 __attribute__((ext_vector_type(4)));

// Round 2 changes:
//  - mask loads are PLAIN (no nontemporal): mask is 208 MB < 256 MB L3, so
//    letting it allocate in Infinity Cache turns steady-state iterations
//    into L3 reads instead of HBM reads.
//  - kernel_launch fires the kernel 3x (idempotent: inputs read-only,
//    output overwritten identically). Probe: dur_us delta vs single launch
//    reveals the true kernel time hidden under the harness fill floor, and
//    repeat dispatches' FETCH_SIZE reveals L3 residency.
__global__ __launch_bounds__(256, 4) void plaq_kernel(
    const float* __restrict__ x,      // (I, N)
    const float* __restrict__ W,      // (O, I, K)
    const float* __restrict__ b,      // (O,)
    const float* __restrict__ mask,   // (N, O, I, K)
    const int*   __restrict__ shifts, // (N, K)
    float* __restrict__ out)          // (O, N)
{
    __shared__ __align__(16) float g_lds[NB][IK];
    const int n0  = blockIdx.x * NB;
    const int tid = threadIdx.x;

    // Gather g[nl][i*13+k] = x[i*N + shifts[(n0+nl)*13+k]]  (1664 elems).
    for (int idx = tid; idx < NB * IK; idx += 256) {
        int nl = idx / IK;
        int r  = idx - nl * IK;
        int i  = r / K_;
        int k  = r - i * K_;
        int s  = shifts[(n0 + nl) * K_ + k];
        g_lds[nl][r] = x[i * N_ + s];
    }

    // Hoist W into registers while the gather is in flight (independent).
    const int o  = tid >> 3;
    const int s8 = tid & 7;
    const f32x4* w4 = (const f32x4*)(W + o * IK);
    f32x4 w[13];
#pragma unroll
    for (int m = 0; m < 13; ++m) w[m] = w4[s8 + 8 * m];
    const float bo = b[o];

    __syncthreads();

    const float scale = (float)((2.0 + 2.0 * M_E) / (M_E - 1.0));

    for (int nl = 0; nl < NB; ++nl) {
        const int n = n0 + nl;
        const f32x4* m4 = (const f32x4*)(mask + (size_t)n * OIK + o * IK);
        const f32x4* g4 = (const f32x4*)(&g_lds[nl][0]);

        float a0 = 0.f, a1 = 0.f, a2 = 0.f, a3 = 0.f;
#pragma unroll
        for (int m = 0; m < 13; ++m) {
            f32x4 mv = m4[s8 + 8 * m];          // plain load: allow L3 allocate
            f32x4 wg = w[m] * g4[s8 + 8 * m];
            a0 = fmaf(mv.x, wg.x, a0);
            a1 = fmaf(mv.y, wg.y, a1);
            a2 = fmaf(mv.z, wg.z, a2);
            a3 = fmaf(mv.w, wg.w, a3);
        }
        float acc = (a0 + a1) + (a2 + a3);

        // Reduce across the 8 lanes sharing this o (within one wave).
        acc += __shfl_down(acc, 4);
        acc += __shfl_down(acc, 2);
        acc += __shfl_down(acc, 1);

        if (s8 == 0) {
            float y  = acc + bo;
            float sg = 1.0f / (1.0f + __expf(-y));
            out[o * N_ + n] = (sg - 0.5f) * scale;
        }
    }
}

extern "C" void kernel_launch(void* const* d_in, const int* in_sizes, int n_in,
                              void* d_out, int out_size, void* d_ws, size_t ws_size,
                              hipStream_t stream) {
    const float* x      = (const float*)d_in[0];
    const float* Wconv  = (const float*)d_in[1];
    const float* bconv  = (const float*)d_in[2];
    const float* mask   = (const float*)d_in[3];
    const int*   shifts = (const int*)d_in[4];
    float* out = (float*)d_out;

    // 3x launch probe: idempotent (pure function of read-only inputs).
    // dur_us_new - dur_us_old = T_first + 2*T_repeat (reveals true kernel
    // time below the harness fill floor; repeats measure L3-warm time).
    plaq_kernel<<<N_ / NB, 256, 0, stream>>>(x, Wconv, bconv, mask, shifts, out);
    plaq_kernel<<<N_ / NB, 256, 0, stream>>>(x, Wconv, bconv, mask, shifts, out);
    plaq_kernel<<<N_ / NB, 256, 0, stream>>>(x, Wconv, bconv, mask, shifts, out);
}

// Round 3
// 305.954 us; speedup vs baseline: 1.2829x; 1.2829x over previous
//
#include <hip/hip_runtime.h>
#include <math.h>

#define O_  32
#define I_  32
#define K_  13
#define N_  4096
#define IK  (I_ * K_)     // 416
#define OIK (O_ * IK)     // 13312
#define NB  4             // n's per block
#define GTOT (NB * IK)    // 1664 gathered elems per block

typedef float f32x4 __attribute__((ext_vector_type(4)));

// Round 3:
//  - single launch (R2's 3x was a timing probe; T_kernel ~= 50us measured)
//  - mask[nl=0] loads issued BEFORE the gather phase: at t=0 all blocks
//    machine-wide are in the latency-bound gather; prefetching starts the
//    HBM stream immediately instead of after ~3-4k dead cycles.
//  - gather restructured to 2 latency levels: 7 batched independent
//    shifts-loads, then 7 batched x-loads. Uniform trip count (clamped),
//    no divergence.
//  - __launch_bounds__(256,3): room for 52 VGPRs of mask prefetch + 52 of W
//    without spill; 12 waves/CU still >> Little's-law need for 6.5 TB/s.
__global__ __launch_bounds__(256, 3) void plaq_kernel(
    const float* __restrict__ x,      // (I, N)
    const float* __restrict__ W,      // (O, I, K)
    const float* __restrict__ b,      // (O,)
    const float* __restrict__ mask,   // (N, O, I, K)
    const int*   __restrict__ shifts, // (N, K)
    float* __restrict__ out)          // (O, N)
{
    __shared__ __align__(16) float g_lds[NB * IK];
    const int n0  = blockIdx.x * NB;
    const int tid = threadIdx.x;
    const int o   = tid >> 3;
    const int s8  = tid & 7;

    // ---- Phase 0: start the mask stream for nl=0 immediately. ----
    const f32x4* m4_0 = (const f32x4*)(mask + (size_t)n0 * OIK + o * IK);
    f32x4 mv0[13];
#pragma unroll
    for (int m = 0; m < 13; ++m) mv0[m] = m4_0[s8 + 8 * m];

    // ---- Phase 1: gather g (2 batched latency levels, no divergence). ----
    int sv[7];
#pragma unroll
    for (int it = 0; it < 7; ++it) {
        int idx = tid + 256 * it; if (idx > GTOT - 1) idx = GTOT - 1;
        int nl  = idx / IK;
        int r   = idx - nl * IK;
        int k   = r - (r / K_) * K_;
        sv[it]  = shifts[(n0 + nl) * K_ + k];      // independent loads
    }
#pragma unroll
    for (int it = 0; it < 7; ++it) {
        int idx = tid + 256 * it; if (idx > GTOT - 1) idx = GTOT - 1;
        int nl  = idx / IK;
        int r   = idx - nl * IK;
        int i   = r / K_;
        g_lds[idx] = x[i * N_ + sv[it]];           // depend only on own sv
    }

    // W into registers (independent of LDS; in flight across the barrier).
    const f32x4* w4 = (const f32x4*)(W + o * IK);
    f32x4 w[13];
#pragma unroll
    for (int m = 0; m < 13; ++m) w[m] = w4[s8 + 8 * m];
    const float bo = b[o];

    __syncthreads();

    const float scale = (float)((2.0 + 2.0 * M_E) / (M_E - 1.0));

    for (int nl = 0; nl < NB; ++nl) {
        const int n = n0 + nl;
        const f32x4* g4 = (const f32x4*)(&g_lds[nl * IK]);
        const f32x4* m4 = (const f32x4*)(mask + (size_t)n * OIK + o * IK);

        float a0 = 0.f, a1 = 0.f, a2 = 0.f, a3 = 0.f;
#pragma unroll
        for (int m = 0; m < 13; ++m) {
            f32x4 mv = (nl == 0) ? mv0[m] : m4[s8 + 8 * m];
            f32x4 wg = w[m] * g4[s8 + 8 * m];
            a0 = fmaf(mv.x, wg.x, a0);
            a1 = fmaf(mv.y, wg.y, a1);
            a2 = fmaf(mv.z, wg.z, a2);
            a3 = fmaf(mv.w, wg.w, a3);
        }
        float acc = (a0 + a1) + (a2 + a3);

        // Reduce across the 8 lanes sharing this o (within one wave).
        acc += __shfl_down(acc, 4);
        acc += __shfl_down(acc, 2);
        acc += __shfl_down(acc, 1);

        if (s8 == 0) {
            float y  = acc + bo;
            float sg = 1.0f / (1.0f + __expf(-y));
            out[o * N_ + n] = (sg - 0.5f) * scale;
        }
    }
}

extern "C" void kernel_launch(void* const* d_in, const int* in_sizes, int n_in,
                              void* d_out, int out_size, void* d_ws, size_t ws_size,
                              hipStream_t stream) {
    const float* x      = (const float*)d_in[0];
    const float* Wconv  = (const float*)d_in[1];
    const float* bconv  = (const float*)d_in[2];
    const float* mask   = (const float*)d_in[3];
    const int*   shifts = (const int*)d_in[4];
    float* out = (float*)d_out;

    plaq_kernel<<<N_ / NB, 256, 0, stream>>>(x, Wconv, bconv, mask, shifts, out);
}